// Round 3
// baseline (1080.160 us; speedup 1.0000x reference)
//
#include <hip/hip_runtime.h>
#include <math.h>

// ---------------------------------------------------------------------------
// VQ-VAE forward, bf16 MFMA implicit-GEMM, 3-deep counted-vmcnt pipeline.
// ---------------------------------------------------------------------------

typedef __attribute__((ext_vector_type(8))) short bf16x8;
typedef __attribute__((ext_vector_type(4))) float f32x4;

__device__ __forceinline__ float bf2f(short s) {
    unsigned u = ((unsigned)(unsigned short)s) << 16;
    return __builtin_bit_cast(float, u);
}
__device__ __forceinline__ unsigned short f2bfu(float f) {
    unsigned u = __builtin_bit_cast(unsigned, f);
    u = (u + 0x7fff + ((u >> 16) & 1)) >> 16;
    return (unsigned short)u;
}
__device__ __forceinline__ short f2bf(float f) { return (short)f2bfu(f); }

template<int ACT>
__device__ __forceinline__ float actf(float v) {
    if (ACT == 1) return fmaxf(v, 0.f);
    if (ACT == 2) return v > 0.f ? v : 0.01f * v;
    return v;
}

__device__ __forceinline__ void gload_lds16(const void* g, void* l) {
    __builtin_amdgcn_global_load_lds(
        (const __attribute__((address_space(1))) unsigned int*)g,
        (__attribute__((address_space(3))) unsigned int*)l, 16, 0, 0);
}

#define WAITV(N) asm volatile("s_waitcnt vmcnt(" #N ")" ::: "memory")

// ----------------------- weight prep: OIHW -> [t][oc][ic] bf16 -------------
__global__ __launch_bounds__(256) void prep_perm_k(const float* __restrict__ src,
        short* __restrict__ dst, int COUT, int CIN, int T, int total) {
    int i = blockIdx.x * 256 + threadIdx.x;
    if (i >= total) return;
    int ic = i % CIN; int r = i / CIN;
    int oc = r % COUT; r /= COUT;
    int t = r % T; int c = r / T;
    dst[i] = f2bf(src[(((size_t)c * COUT + oc) * CIN + ic) * T + t]);
}

// tw0 (Cin256,Cout128,4,4) -> [parity(4)][tap(4)][oc128][ic256]
__global__ __launch_bounds__(256) void prep_tw0_k(const float* __restrict__ src,
        short* __restrict__ dst) {
    int i = blockIdx.x * 256 + threadIdx.x;
    if (i >= 4 * 4 * 128 * 256) return;
    int ic = i & 255; int r = i >> 8;
    int oc = r & 127; r >>= 7;
    int tap = r & 3; int par = r >> 2;
    int py = par >> 1, px = par & 1, my = tap >> 1, mx = tap & 1;
    int ky = 2 * my + (py ^ 1), kx = 2 * mx + (px ^ 1);
    dst[i] = f2bf(src[(((size_t)ic * 128 + oc) * 4 + ky) * 4 + kx]);
}

// ------------------- unified MFMA implicit-GEMM conv -----------------------
template<int CIN, int COUT, int NTAPS, int TAPPAT, int SM, int INW,
         int OUTACT, bool RES, bool HASB, int OUTMODE, int BN>
__global__ __launch_bounds__(256) void gconv_k(
        const short* __restrict__ in, const short* __restrict__ Wp,
        const float* __restrict__ bias, const short* __restrict__ res,
        void* __restrict__ outp, int py, int px) {
    constexpr int KCH = CIN / 32;
    constexpr int LG = (KCH == 8) ? 3 : (KCH == 4) ? 2 : (KCH == 2) ? 1 : 0;
    constexpr int ST = NTAPS * KCH;
    constexpr int NF = BN / 32;
    constexpr int WN = BN / 2;
    __shared__ short sA[3 * 128 * 32];
    __shared__ short sB[3 * BN * 32];
    const int tid = threadIdx.x;
    const int lane = tid & 63, wv = tid >> 6;
    const int wr = wv >> 1, wc = wv & 1;
    const int pix0 = blockIdx.x * 128;
    const int oc0 = blockIdx.y * BN;

    const int sp = tid >> 2;
    const int fsp = (sp & 3) ^ ((sp >> 2) & 3);
    const int swz = ((tid & 3) ^ fsp) * 8;
    int rbA[2];
#pragma unroll
    for (int rd = 0; rd < 2; rd++) {
        int pix = pix0 + sp + rd * 64;
        int b = pix >> 10, Y = (pix >> 5) & 31, X = pix & 31;
        rbA[rd] = ((b * INW + SM * Y + 2) * INW + (SM * X + 2)) * CIN + swz;
    }
    const int wb0 = (oc0 + sp) * CIN + swz;
    const int wb1 = (oc0 + sp + 64) * CIN + swz;

    f32x4 acc[4][NF];
#pragma unroll
    for (int i = 0; i < 4; i++)
#pragma unroll
        for (int j = 0; j < NF; j++) acc[i][j] = f32x4{0.f, 0.f, 0.f, 0.f};

    const int fr = (lane & 3) ^ ((lane >> 2) & 3);
    const int sslot = ((lane >> 4) ^ fr) * 8;
    const int abase = (wr * 64 + (lane & 15)) * 32 + sslot;
    const int bbase = (wc * WN + (lane & 15)) * 32 + sslot;

    auto stage = [&](int s, int bi) {
        int t = s >> LG, c = s & (KCH - 1);
        int rof, cof;
        if (TAPPAT == 0) { rof = 0; cof = 0; }
        else if (TAPPAT == 1) { rof = t / 3 - 1; cof = t % 3 - 1; }
        else if (TAPPAT == 2) { rof = t / 4 - 1; cof = t % 4 - 1; }
        else { int my = t >> 1, mx = t & 1;
               rof = (py == 0) ? -my : 1 - my;
               cof = (px == 0) ? -mx : 1 - mx; }
        const int tapoff = (rof * INW + cof) * CIN + c * 32;
        char* a = (char*)sA + bi * 8192;
        char* b = (char*)sB + bi * (BN * 64);
        const short* wt = Wp + (size_t)t * COUT * CIN + c * 32;
        gload_lds16(in + rbA[0] + tapoff, a + tid * 16);
        gload_lds16(in + rbA[1] + tapoff, a + 4096 + tid * 16);
        gload_lds16(wt + wb0, b + tid * 16);
        if (BN == 128) gload_lds16(wt + wb1, b + 4096 + tid * 16);
    };

    stage(0, 0);
    stage(1, 1);
    int cur = 0;
    for (int s = 0; s < ST; ++s) {
        if (s < ST - 1) {
            if (BN == 128) WAITV(4); else WAITV(3);
        } else {
            WAITV(0);
        }
        __builtin_amdgcn_s_barrier();
        int nxt = cur + 2; if (nxt >= 3) nxt -= 3;
        if (s + 2 < ST) stage(s + 2, nxt);
        const short* a = sA + cur * 4096;
        const short* b = sB + cur * (BN * 32);
        bf16x8 af[4], bfm[NF];
#pragma unroll
        for (int mi = 0; mi < 4; mi++)
            af[mi] = *(const bf16x8*)(a + abase + mi * 512);
#pragma unroll
        for (int ni = 0; ni < NF; ni++)
            bfm[ni] = *(const bf16x8*)(b + bbase + ni * 512);
        __builtin_amdgcn_s_setprio(1);
#pragma unroll
        for (int mi = 0; mi < 4; mi++)
#pragma unroll
            for (int ni = 0; ni < NF; ni++)
                acc[mi][ni] = __builtin_amdgcn_mfma_f32_16x16x32_bf16(
                    af[mi], bfm[ni], acc[mi][ni], 0, 0, 0);
        __builtin_amdgcn_s_setprio(0);
        cur = (cur == 2) ? 0 : cur + 1;
    }
    // epilogue
#pragma unroll
    for (int mi = 0; mi < 4; mi++) {
#pragma unroll
        for (int r = 0; r < 4; r++) {
            int pix = pix0 + wr * 64 + mi * 16 + (lane >> 4) * 4 + r;
            int b = pix >> 10, Y = (pix >> 5) & 31, X = pix & 31;
            size_t rowoff = 0;
            if (OUTMODE == 0)
                rowoff = (((size_t)b * 36 + Y + 2) * 36 + X + 2) * COUT;
            else if (OUTMODE == 2)
                rowoff = (((size_t)b * 68 + 2 * Y + py + 2) * 68 + 2 * X + px + 2) * 128;
#pragma unroll
            for (int ni = 0; ni < NF; ni++) {
                int col = oc0 + wc * WN + ni * 16 + (lane & 15);
                float v = acc[mi][ni][r];
                if (HASB) v += bias[col];
                if (OUTMODE == 1) {
                    ((float*)outp)[(size_t)pix * COUT + col] = actf<OUTACT>(v);
                } else {
                    size_t off = rowoff + col;
                    if (RES) v += bf2f(res[off]);
                    ((short*)outp)[off] = f2bf(actf<OUTACT>(v));
                }
            }
        }
    }
}

// ------------------------- conv0: 4x4 s2 p1, Cin=3 -------------------------
__global__ __launch_bounds__(256) void conv0_k(const float* __restrict__ x,
        const float* __restrict__ W, const float* __restrict__ bias,
        short* __restrict__ P0) {
    __shared__ float sIn[3 * 18 * 66];
    __shared__ float sW[48 * 32];
    int b = blockIdx.z, ocg = blockIdx.y, tile = blockIdx.x;
    int y0 = (tile >> 1) * 8, x0 = (tile & 1) * 32;
    int tid = threadIdx.x;
    for (int t = tid; t < 1536; t += 256) {
        int k = t >> 5, oc = t & 31;
        sW[t] = W[(size_t)(ocg * 32 + oc) * 48 + k];
    }
    for (int t = tid; t < 3 * 18 * 66; t += 256) {
        int ic = t / 1188; int rem = t - ic * 1188;
        int ry = rem / 66, rx = rem - ry * 66;
        int iy = 2 * y0 - 1 + ry, ix = 2 * x0 - 1 + rx;
        float v = 0.f;
        if ((unsigned)iy < 128u && (unsigned)ix < 128u)
            v = x[((size_t)b * 3 + ic) * 16384 + iy * 128 + ix];
        sIn[t] = v;
    }
    __syncthreads();
    int r = tid >> 5, cx = tid & 31;
    float acc[32];
#pragma unroll
    for (int o = 0; o < 32; o++) acc[o] = 0.f;
#pragma unroll
    for (int ic = 0; ic < 3; ic++) {
#pragma unroll
        for (int k = 0; k < 16; k++) {
            int ky = k >> 2, kx = k & 3;
            float xv = sIn[ic * 1188 + (2 * r + ky) * 66 + 2 * cx + kx];
            const float4* wp = (const float4*)(sW + (ic * 16 + k) * 32);
#pragma unroll
            for (int q = 0; q < 8; q++) {
                float4 w = wp[q];
                acc[4 * q + 0] += w.x * xv; acc[4 * q + 1] += w.y * xv;
                acc[4 * q + 2] += w.z * xv; acc[4 * q + 3] += w.w * xv;
            }
        }
    }
    size_t base = (((size_t)b * 68 + y0 + r + 2) * 68 + x0 + cx + 2) * 128 + ocg * 32;
#pragma unroll
    for (int q = 0; q < 16; q++) {
        float v0 = actf<2>(acc[2 * q] + bias[ocg * 32 + 2 * q]);
        float v1 = actf<2>(acc[2 * q + 1] + bias[ocg * 32 + 2 * q + 1]);
        ((int*)(P0 + base))[q] = (int)f2bfu(v0) | ((int)f2bfu(v1) << 16);
    }
}

// ------------------------------- VQ argmin (MFMA) --------------------------
// scores = ||c||^2 - 2 z.c over [128 pix] x [512 codes], K=64.
__global__ __launch_bounds__(256) void vq_argmin_k(const float* __restrict__ zr,
        const float* __restrict__ cb, int* __restrict__ ind) {
    __shared__ short sZ[2][128 * 32];   // [kc][row][32] swizzled
    __shared__ short sC[2][128 * 32];
    __shared__ float sN[128];
    const int tid = threadIdx.x;
    const int lane = tid & 63, wv = tid >> 6;
    const int pos0 = blockIdx.x * 128;

    // stage Z tile (fp32 -> bf16, swizzled)
#pragma unroll
    for (int it = 0; it < 4; ++it) {
        int task = tid + it * 256;
        int row = task >> 3, kq = task & 7;
        const float4* zp = (const float4*)(zr + (size_t)(pos0 + row) * 64 + kq * 8);
        float4 v0 = zp[0], v1 = zp[1];
        int f = (row & 3) ^ ((row >> 2) & 3);
        int slot = ((kq & 3) ^ f) * 8;
        short tmp[8] = {f2bf(v0.x), f2bf(v0.y), f2bf(v0.z), f2bf(v0.w),
                        f2bf(v1.x), f2bf(v1.y), f2bf(v1.z), f2bf(v1.w)};
        *(bf16x8*)&sZ[kq >> 2][row * 32 + slot] = *(bf16x8*)tmp;
    }

    const int fr = (lane & 3) ^ ((lane >> 2) & 3);
    const int sslot = ((lane >> 4) ^ fr) * 8;
    const int l15 = lane & 15;

    float best[2][4]; int bidx[2][4];
#pragma unroll
    for (int mi = 0; mi < 2; mi++)
#pragma unroll
        for (int r = 0; r < 4; r++) { best[mi][r] = INFINITY; bidx[mi][r] = 0; }

    for (int ch = 0; ch < 4; ++ch) {
        __syncthreads();   // prev chunk reads done (and Z writes at ch=0)
#pragma unroll
        for (int it = 0; it < 4; ++it) {
            int task = tid + it * 256;
            int row = task >> 3, kq = task & 7;
            const float4* cp = (const float4*)(cb + (size_t)(ch * 128 + row) * 64 + kq * 8);
            float4 v0 = cp[0], v1 = cp[1];
            int f = (row & 3) ^ ((row >> 2) & 3);
            int slot = ((kq & 3) ^ f) * 8;
            short tmp[8] = {f2bf(v0.x), f2bf(v0.y), f2bf(v0.z), f2bf(v0.w),
                            f2bf(v1.x), f2bf(v1.y), f2bf(v1.z), f2bf(v1.w)};
            *(bf16x8*)&sC[kq >> 2][row * 32 + slot] = *(bf16x8*)tmp;
        }
        if (tid < 128) {
            const float4* cp = (const float4*)(cb + (size_t)(ch * 128 + tid) * 64);
            float s = 0.f;
#pragma unroll
            for (int q = 0; q < 16; q++) {
                float4 v = cp[q];
                s += v.x * v.x + v.y * v.y + v.z * v.z + v.w * v.w;
            }
            sN[tid] = s;
        }
        __syncthreads();
        f32x4 acc[2][8];
#pragma unroll
        for (int mi = 0; mi < 2; mi++)
#pragma unroll
            for (int ni = 0; ni < 8; ni++) acc[mi][ni] = f32x4{0.f, 0.f, 0.f, 0.f};
#pragma unroll
        for (int kc = 0; kc < 2; ++kc) {
            bf16x8 za[2], ca[8];
#pragma unroll
            for (int mi = 0; mi < 2; mi++)
                za[mi] = *(const bf16x8*)&sZ[kc][(wv * 32 + mi * 16 + l15) * 32 + sslot];
#pragma unroll
            for (int ni = 0; ni < 8; ni++)
                ca[ni] = *(const bf16x8*)&sC[kc][(ni * 16 + l15) * 32 + sslot];
#pragma unroll
            for (int mi = 0; mi < 2; mi++)
#pragma unroll
                for (int ni = 0; ni < 8; ni++)
                    acc[mi][ni] = __builtin_amdgcn_mfma_f32_16x16x32_bf16(
                        za[mi], ca[ni], acc[mi][ni], 0, 0, 0);
        }
#pragma unroll
        for (int mi = 0; mi < 2; mi++)
#pragma unroll
            for (int ni = 0; ni < 8; ni++) {
                float nrm = sN[ni * 16 + l15];
                int idx = ch * 128 + ni * 16 + l15;
#pragma unroll
                for (int r = 0; r < 4; r++) {
                    float sc = nrm - 2.f * acc[mi][ni][r];
                    if (sc < best[mi][r]) { best[mi][r] = sc; bidx[mi][r] = idx; }
                }
            }
    }
    // reduce across the 16 cols (lane low bits), first-index tie-break
#pragma unroll
    for (int m = 1; m < 16; m <<= 1) {
#pragma unroll
        for (int mi = 0; mi < 2; mi++)
#pragma unroll
            for (int r = 0; r < 4; r++) {
                float os = __shfl_xor(best[mi][r], m);
                int   oi = __shfl_xor(bidx[mi][r], m);
                if (os < best[mi][r] || (os == best[mi][r] && oi < bidx[mi][r])) {
                    best[mi][r] = os; bidx[mi][r] = oi;
                }
            }
    }
    if (l15 == 0) {
        int g = lane >> 4;
#pragma unroll
        for (int mi = 0; mi < 2; mi++)
#pragma unroll
            for (int r = 0; r < 4; r++)
                ind[pos0 + wv * 32 + mi * 16 + g * 4 + r] = bidx[mi][r];
    }
}

// -------------- VQ gather -> Pq padded bf16 + loss partials ----------------
__global__ __launch_bounds__(256) void vq_gather_k(const float* __restrict__ zr,
        const float* __restrict__ cb, const int* __restrict__ ind,
        short* __restrict__ q, float* __restrict__ part) {
    int pos = blockIdx.x * 256 + threadIdx.x;
    int b = pos >> 10, hw = pos & 1023, y = hw >> 5, xx = hw & 31;
    int idx = ind[pos];
    const float4* cp = (const float4*)(cb + (size_t)idx * 64);
    const float4* zp = (const float4*)(zr + (size_t)pos * 64);
    size_t qb = (((size_t)b * 36 + y + 2) * 36 + xx + 2) * 64;
    float sum = 0.f;
#pragma unroll
    for (int d4 = 0; d4 < 16; d4++) {
        float4 c = cp[d4], z = zp[d4];
        float dx = c.x - z.x, dy = c.y - z.y, dz = c.z - z.z, dw = c.w - z.w;
        sum += dx * dx + dy * dy + dz * dz + dw * dw;
        ((int*)(q + qb))[2 * d4] = (int)f2bfu(c.x) | ((int)f2bfu(c.y) << 16);
        ((int*)(q + qb))[2 * d4 + 1] = (int)f2bfu(c.z) | ((int)f2bfu(c.w) << 16);
    }
#pragma unroll
    for (int m = 1; m < 64; m <<= 1) sum += __shfl_xor(sum, m);
    __shared__ float sred[4];
    int lane = threadIdx.x & 63, wvv = threadIdx.x >> 6;
    if (lane == 0) sred[wvv] = sum;
    __syncthreads();
    if (threadIdx.x == 0)
        part[blockIdx.x] = sred[0] + sred[1] + sred[2] + sred[3];
}

__global__ void finalize_k(const float* __restrict__ part, float* __restrict__ out) {
    if (threadIdx.x == 0) {
        float s = 0.f;
        for (int k = 0; k < 64; k++) s += part[k];
        float m = s / 1048576.f;
        out[786432] = m;
        out[786433] = m;
    }
}

// -------- tw1: ConvT 4x4 s2 p1, 128->3, input padded-68 bf16, tanh ---------
__global__ __launch_bounds__(256) void tw1_k(const short* __restrict__ in,
        const float* __restrict__ W, const float* __restrict__ bias,
        float* __restrict__ out) {
    __shared__ float sW[16 * 128 * 4];
    int b = blockIdx.y, y0 = blockIdx.x * 8;
    int tid = threadIdx.x;
    for (int t = tid; t < 2048; t += 256) {
        int k = t >> 7, ic = t & 127;
        float4 v;
        v.x = W[((size_t)ic * 3 + 0) * 16 + k];
        v.y = W[((size_t)ic * 3 + 1) * 16 + k];
        v.z = W[((size_t)ic * 3 + 2) * 16 + k];
        v.w = 0.f;
        *(float4*)&sW[t * 4] = v;
    }
    __syncthreads();
    int r = tid >> 5, g = tid & 31;
    int oy = y0 + r, py = oy & 1, Y = oy >> 1, pxp = g & 1;
    float acc[4][3];
#pragma unroll
    for (int p = 0; p < 4; p++)
#pragma unroll
        for (int o = 0; o < 3; o++) acc[p][o] = 0.f;
#pragma unroll
    for (int my = 0; my < 2; my++) {
        int iy = Y + ((py == 0) ? -my : 1 - my) + 2;
        const short* rowp = in + (((size_t)b * 68 + iy) * 68) * 128;
        int ky = 2 * my + (py ^ 1);
#pragma unroll
        for (int mx = 0; mx < 2; mx++) {
            int kx = 2 * mx + (pxp ^ 1);
            int cof = ((pxp == 0) ? -mx : 1 - mx) + 2;
            const float* wbase = &sW[((ky * 4 + kx) * 128) * 4];
            const short* pptr[4];
#pragma unroll
            for (int p = 0; p < 4; p++) {
                int X = ((g + 32 * p) >> 1) + cof;
                pptr[p] = rowp + (size_t)X * 128;
            }
            for (int icb = 0; icb < 16; icb++) {
                bf16x8 v[4];
#pragma unroll
                for (int p = 0; p < 4; p++)
                    v[p] = *(const bf16x8*)(pptr[p] + icb * 8);
#pragma unroll
                for (int j = 0; j < 8; j++) {
                    float4 w = *(const float4*)&wbase[(icb * 8 + j) * 4];
#pragma unroll
                    for (int p = 0; p < 4; p++) {
                        float xv = bf2f(v[p][j]);
                        acc[p][0] += w.x * xv;
                        acc[p][1] += w.y * xv;
                        acc[p][2] += w.z * xv;
                    }
                }
            }
        }
    }
#pragma unroll
    for (int p = 0; p < 4; p++) {
        int ox = g + 32 * p;
#pragma unroll
        for (int o = 0; o < 3; o++)
            out[(((size_t)b * 3 + o) << 14) + oy * 128 + ox] =
                tanhf(acc[p][o] + bias[o]);
    }
}

// ---------------------------------------------------------------------------
extern "C" void kernel_launch(void* const* d_in, const int* in_sizes, int n_in,
                              void* d_out, int out_size, void* d_ws, size_t ws_size,
                              hipStream_t stream) {
    const float* x    = (const float*)d_in[0];
    const float* ew0  = (const float*)d_in[1];
    const float* eb0  = (const float*)d_in[2];
    const float* ew1  = (const float*)d_in[3];
    const float* eb1  = (const float*)d_in[4];
    const float* ew2  = (const float*)d_in[5];
    const float* eb2  = (const float*)d_in[6];
    const float* erw3 = (const float*)d_in[7];
    const float* erw1 = (const float*)d_in[8];
    const float* ew3  = (const float*)d_in[9];
    const float* eb3  = (const float*)d_in[10];
    const float* cbk  = (const float*)d_in[11];
    const float* dw0  = (const float*)d_in[12];
    const float* db0  = (const float*)d_in[13];
    const float* drw3 = (const float*)d_in[14];
    const float* drw1 = (const float*)d_in[15];
    const float* tw0  = (const float*)d_in[16];
    const float* tb0  = (const float*)d_in[17];
    const float* tw1  = (const float*)d_in[18];
    const float* tb1  = (const float*)d_in[19];
    float* out = (float*)d_out;

    short* S = (short*)d_ws;
    short* P0  = S;                       // [16][68][68][128]
    short* PB  = P0 + 9469952;            // [16][36][36][256]
    short* PC  = PB + 5308416;
    short* Pq  = PC + 5308416;            // [16][36][36][64]
    short* Wp1 = Pq + 1327104;
    short* We2 = Wp1 + 524288;
    short* Wer3 = We2 + 589824;
    short* We11 = Wer3 + 3538944;
    short* Wz   = We11 + 393216;
    short* Wd0  = Wz + 16384;
    short* Wdr3 = Wd0 + 147456;
    short* Wdr1 = Wdr3 + 3538944;
    short* Wt0  = Wdr1 + 393216;
    float* F   = (float*)(S + 31080448);
    float* Zr  = F;                       // [16384][64]
    float* PART = Zr + 1048576;
    int*   IND = (int*)(PART + 64);

    hipMemsetAsync(d_ws, 0, (size_t)21413888 * 2, stream);

    auto gp = [](int n) { return dim3((n + 255) / 256); };
    prep_perm_k<<<gp(524288), 256, 0, stream>>>(ew1, Wp1, 256, 128, 16, 524288);
    prep_perm_k<<<gp(589824), 256, 0, stream>>>(ew2, We2, 256, 256, 9, 589824);
    prep_perm_k<<<gp(3538944), 256, 0, stream>>>(erw3, Wer3, 256, 256, 9, 3538944);
    prep_perm_k<<<gp(393216), 256, 0, stream>>>(erw1, We11, 256, 256, 1, 393216);
    prep_perm_k<<<gp(16384), 256, 0, stream>>>(ew3, Wz, 64, 256, 1, 16384);
    prep_perm_k<<<gp(147456), 256, 0, stream>>>(dw0, Wd0, 256, 64, 9, 147456);
    prep_perm_k<<<gp(3538944), 256, 0, stream>>>(drw3, Wdr3, 256, 256, 9, 3538944);
    prep_perm_k<<<gp(393216), 256, 0, stream>>>(drw1, Wdr1, 256, 256, 1, 393216);
    prep_tw0_k<<<gp(524288), 256, 0, stream>>>(tw0, Wt0);

    // ---------------- encoder ----------------
    conv0_k<<<dim3(16, 4, 16), 256, 0, stream>>>(x, ew0, eb0, P0);
    gconv_k<128, 256, 16, 2, 2, 68, 2, false, true, 0, 128>
        <<<dim3(128, 2), 256, 0, stream>>>(P0, Wp1, eb1, nullptr, PB, 0, 0);
    gconv_k<256, 256, 9, 1, 1, 36, 2, false, true, 0, 128>
        <<<dim3(128, 2), 256, 0, stream>>>(PB, We2, eb2, nullptr, PC, 0, 0);
    for (int i = 0; i < 6; i++) {
        gconv_k<256, 256, 9, 1, 1, 36, 1, false, false, 0, 128>
            <<<dim3(128, 2), 256, 0, stream>>>(PC, Wer3 + (size_t)i * 589824,
                                               nullptr, nullptr, PB, 0, 0);
        if (i < 5)
            gconv_k<256, 256, 1, 0, 1, 36, 0, true, false, 0, 128>
                <<<dim3(128, 2), 256, 0, stream>>>(PB, We11 + (size_t)i * 65536,
                                                   nullptr, PC, PC, 0, 0);
        else
            gconv_k<256, 256, 1, 0, 1, 36, 2, true, false, 0, 128>
                <<<dim3(128, 2), 256, 0, stream>>>(PB, We11 + (size_t)i * 65536,
                                                   nullptr, PC, PC, 0, 0);
    }
    gconv_k<256, 64, 1, 0, 1, 36, 2, false, true, 1, 64>
        <<<dim3(128, 1), 256, 0, stream>>>(PC, Wz, eb3, nullptr, Zr, 0, 0);

    // ---------------- vector quantization ----------------
    vq_argmin_k<<<128, 256, 0, stream>>>(Zr, cbk, IND);
    vq_gather_k<<<64, 256, 0, stream>>>(Zr, cbk, IND, Pq, PART);

    // ---------------- decoder ----------------
    gconv_k<64, 256, 9, 1, 1, 36, 2, false, true, 0, 128>
        <<<dim3(128, 2), 256, 0, stream>>>(Pq, Wd0, db0, nullptr, PC, 0, 0);
    for (int i = 0; i < 6; i++) {
        gconv_k<256, 256, 9, 1, 1, 36, 1, false, false, 0, 128>
            <<<dim3(128, 2), 256, 0, stream>>>(PC, Wdr3 + (size_t)i * 589824,
                                               nullptr, nullptr, PB, 0, 0);
        if (i < 5)
            gconv_k<256, 256, 1, 0, 1, 36, 0, true, false, 0, 128>
                <<<dim3(128, 2), 256, 0, stream>>>(PB, Wdr1 + (size_t)i * 65536,
                                                   nullptr, PC, PC, 0, 0);
        else
            gconv_k<256, 256, 1, 0, 1, 36, 2, true, false, 0, 128>
                <<<dim3(128, 2), 256, 0, stream>>>(PB, Wdr1 + (size_t)i * 65536,
                                                   nullptr, PC, PC, 0, 0);
    }
    for (int par = 0; par < 4; par++) {
        int py = par >> 1, px = par & 1;
        gconv_k<256, 128, 4, 3, 1, 36, 2, false, true, 2, 128>
            <<<dim3(128, 1), 256, 0, stream>>>(PC, Wt0 + (size_t)par * 131072,
                                               tb0, nullptr, P0, py, px);
    }
    tw1_k<<<dim3(16, 16), 256, 0, stream>>>(P0, tw1, tb1, out);

    finalize_k<<<1, 64, 0, stream>>>(PART, out);
}

// Round 4
// 632.083 us; speedup vs baseline: 1.7089x; 1.7089x over previous
//
#include <hip/hip_runtime.h>
#include <math.h>

// ---------------------------------------------------------------------------
// VQ-VAE forward. bf16 MFMA implicit-GEMM.
// rconv_k: 8-wave (2/SIMD) BM=64 x BN=256 blocks, KB=64, 3-buf counted-vmcnt
// pipeline, optional fused residual-1x1 (phase2 via LDS h tile).
// ---------------------------------------------------------------------------

typedef __attribute__((ext_vector_type(8))) short bf16x8;
typedef __attribute__((ext_vector_type(4))) float f32x4;

__device__ __forceinline__ float bf2f(short s) {
    unsigned u = ((unsigned)(unsigned short)s) << 16;
    return __builtin_bit_cast(float, u);
}
__device__ __forceinline__ unsigned short f2bfu(float f) {
    unsigned u = __builtin_bit_cast(unsigned, f);
    u = (u + 0x7fff + ((u >> 16) & 1)) >> 16;
    return (unsigned short)u;
}
__device__ __forceinline__ short f2bf(float f) { return (short)f2bfu(f); }

template<int ACT>
__device__ __forceinline__ float actf(float v) {
    if (ACT == 1) return fmaxf(v, 0.f);
    if (ACT == 2) return v > 0.f ? v : 0.01f * v;
    return v;
}

__device__ __forceinline__ void gload_lds16(const void* g, void* l) {
    __builtin_amdgcn_global_load_lds(
        (const __attribute__((address_space(1))) unsigned int*)g,
        (__attribute__((address_space(3))) unsigned int*)l, 16, 0, 0);
}

__device__ __forceinline__ int fof(int r) { return (r & 3) ^ ((r >> 2) & 3); }

#define WAITV(N) asm volatile("s_waitcnt vmcnt(" #N ")" ::: "memory")

// ----------------------- weight prep: OIHW -> [t][oc][ic] bf16 -------------
__global__ __launch_bounds__(256) void prep_perm_k(const float* __restrict__ src,
        short* __restrict__ dst, int COUT, int CIN, int T, int total) {
    int i = blockIdx.x * 256 + threadIdx.x;
    if (i >= total) return;
    int ic = i % CIN; int r = i / CIN;
    int oc = r % COUT; r /= COUT;
    int t = r % T; int c = r / T;
    dst[i] = f2bf(src[(((size_t)c * COUT + oc) * CIN + ic) * T + t]);
}

// tw0 (Cin256,Cout128,4,4) -> [parity(4)][tap(4)][oc128][ic256]
__global__ __launch_bounds__(256) void prep_tw0_k(const float* __restrict__ src,
        short* __restrict__ dst) {
    int i = blockIdx.x * 256 + threadIdx.x;
    if (i >= 4 * 4 * 128 * 256) return;
    int ic = i & 255; int r = i >> 8;
    int oc = r & 127; r >>= 7;
    int tap = r & 3; int par = r >> 2;
    int py = par >> 1, px = par & 1, my = tap >> 1, mx = tap & 1;
    int ky = 2 * my + (py ^ 1), kx = 2 * mx + (px ^ 1);
    dst[i] = f2bf(src[(((size_t)ic * 128 + oc) * 4 + ky) * 4 + kx]);
}

// ---------------- rconv: 8-wave BM=64 BN=256 implicit-GEMM conv ------------
// in: padded NHWC bf16 (halo 2).  Wp: [tap][256][CIN].  out: padded-36 x 256.
// FUSE: phase2 computes out = act(in + W1 @ relu(conv)) (residual 1x1).
template<int CIN, int NTAPS, int TAPPAT, int SM, int INW, int OUTACT,
         bool HASB, bool FUSE>
__global__ __launch_bounds__(512, 1) void rconv_k(
        const short* __restrict__ in, const short* __restrict__ Wp,
        const float* __restrict__ bias, const short* __restrict__ W1p,
        short* __restrict__ outp) {
    constexpr int CH64 = (CIN >= 128) ? CIN / 64 : 1;
    constexpr int LG2 = (CH64 == 4) ? 2 : (CH64 == 2) ? 1 : 0;
    constexpr int ST = NTAPS * CH64;
    __shared__ short sLds[FUSE ? 77824 : 61440];  // 3x40KB staging (+32KB h)
    const int tid = threadIdx.x;
    const int lane = tid & 63, wv = tid >> 6;
    const int wr = wv >> 2, wc = wv & 3;
    const int pix0 = blockIdx.x * 64;
    const int l15 = lane & 15, hi = lane >> 4;
    const int sl = (hi ^ fof(l15)) * 8;

    // ---- staging source pointers (per-thread constant parts) ----
    const int arow = (tid >> 2) & 63, akk = tid >> 8, aslot = tid & 3;
    const short* Aptr;
    {
        int pixa = pix0 + arow;
        int ba = pixa >> 10, Ya = (pixa >> 5) & 31, Xa = pixa & 31;
        Aptr = in + (size_t)((ba * INW + SM * Ya + 2) * INW + (SM * Xa + 2)) * CIN
                  + akk * 32 + (aslot ^ fof(arow)) * 8;
    }
    const short* Bptr[4];
#pragma unroll
    for (int j = 0; j < 4; j++) {
        int gb = tid + 512 * j;
        int kkb = gb >> 10, oc = (gb >> 2) & 255, slb = gb & 3;
        Bptr[j] = Wp + (size_t)oc * CIN + kkb * 32 + ((slb ^ fof(oc)) * 8);
    }

    auto stage = [&](int s, int bi) {
        int t = s >> LG2;
        int c0 = (s & (CH64 - 1)) * 64;
        int rof, cof;
        if (TAPPAT == 1) { rof = t / 3 - 1; cof = t % 3 - 1; }
        else             { rof = (t >> 2) - 1; cof = (t & 3) - 1; }
        int aoff = (rof * INW + cof) * CIN + c0;
        int woff = t * (256 * CIN) + c0;
        char* L = (char*)sLds + bi * 40960;
        gload_lds16(Aptr + aoff, L + tid * 16);
#pragma unroll
        for (int j = 0; j < 4; j++)
            gload_lds16(Bptr[j] + woff, L + 8192 + (tid + 512 * j) * 16);
    };

    f32x4 acc[2][4];
#pragma unroll
    for (int mi = 0; mi < 2; mi++)
#pragma unroll
        for (int ni = 0; ni < 4; ni++) acc[mi][ni] = f32x4{0.f, 0.f, 0.f, 0.f};

    stage(0, 0);
    stage(1, 1);
    int bi = 0;
    for (int s = 0; s < ST; ++s) {
        if (s < ST - 1) { WAITV(5); } else { WAITV(0); }
        __builtin_amdgcn_s_barrier();
        int nx = bi + 2; if (nx >= 3) nx -= 3;
        if (s + 2 < ST) stage(s + 2, nx);
        const short* L = sLds + bi * 20480;
        const short* LB = L + 4096;
        bf16x8 af[2][2], bfr[4][2];
#pragma unroll
        for (int kk = 0; kk < 2; kk++) {
#pragma unroll
            for (int mi = 0; mi < 2; mi++)
                af[mi][kk] = *(const bf16x8*)(L + kk * 2048
                    + (wr * 32 + mi * 16 + l15) * 32 + sl);
#pragma unroll
            for (int ni = 0; ni < 4; ni++)
                bfr[ni][kk] = *(const bf16x8*)(LB + kk * 8192
                    + (wc * 64 + ni * 16 + l15) * 32 + sl);
        }
        __builtin_amdgcn_s_setprio(1);
#pragma unroll
        for (int kk = 0; kk < 2; kk++)
#pragma unroll
            for (int mi = 0; mi < 2; mi++)
#pragma unroll
                for (int ni = 0; ni < 4; ni++)
                    acc[mi][ni] = __builtin_amdgcn_mfma_f32_16x16x32_bf16(
                        af[mi][kk], bfr[ni][kk], acc[mi][ni], 0, 0, 0);
        __builtin_amdgcn_s_setprio(0);
        bi = (bi == 2) ? 0 : bi + 1;
    }

    if (!FUSE) {
#pragma unroll
        for (int mi = 0; mi < 2; mi++)
#pragma unroll
            for (int r = 0; r < 4; r++) {
                int lrow = wr * 32 + mi * 16 + hi * 4 + r;
                int pix = pix0 + lrow;
                int b = pix >> 10, Y = (pix >> 5) & 31, X = pix & 31;
                size_t base = (((size_t)b * 36 + Y + 2) * 36 + X + 2) * 256;
#pragma unroll
                for (int ni = 0; ni < 4; ni++) {
                    int col = wc * 64 + ni * 16 + l15;
                    float v = acc[mi][ni][r];
                    if (HASB) v += bias[col];
                    outp[base + col] = f2bf(actf<OUTACT>(v));
                }
            }
        return;
    }

    // ---------------- FUSE phase boundary: h -> LDS (relu) ----------------
    short* H = sLds + 61440;
#pragma unroll
    for (int mi = 0; mi < 2; mi++)
#pragma unroll
        for (int r = 0; r < 4; r++) {
            int lrow = wr * 32 + mi * 16 + hi * 4 + r;
            int frow = fof(lrow);
#pragma unroll
            for (int ni = 0; ni < 4; ni++) {
                int col = wc * 64 + ni * 16 + l15;
                H[((col >> 5) * 64 + lrow) * 32 + (((col >> 3) & 3) ^ frow) * 8
                  + (col & 7)] = f2bf(fmaxf(acc[mi][ni][r], 0.f));
            }
        }

    const short* W1ptr[4];
#pragma unroll
    for (int j = 0; j < 4; j++) {
        int gb = tid + 512 * j;
        int kkb = gb >> 10, oc = (gb >> 2) & 255, slb = gb & 3;
        W1ptr[j] = W1p + (size_t)oc * 256 + kkb * 32 + ((slb ^ fof(oc)) * 8);
    }
    auto stage2 = [&](int s2, int bb) {
        char* L = (char*)sLds + bb * 40960 + 8192;
#pragma unroll
        for (int j = 0; j < 4; j++)
            gload_lds16(W1ptr[j] + s2 * 64, L + (tid + 512 * j) * 16);
    };
    stage2(0, 0);
    stage2(1, 1);
    __syncthreads();   // h visible to all waves (drains counters; once/block)

    f32x4 acc2[2][4];
#pragma unroll
    for (int mi = 0; mi < 2; mi++)
#pragma unroll
        for (int ni = 0; ni < 4; ni++) acc2[mi][ni] = f32x4{0.f, 0.f, 0.f, 0.f};

    for (int s2 = 0; s2 < 4; ++s2) {
        if (s2 < 3) { WAITV(4); } else { WAITV(0); }
        __builtin_amdgcn_s_barrier();
        if (s2 == 0) stage2(2, 2);
        if (s2 == 1) stage2(3, 0);
        const short* LB = sLds + ((s2 < 3) ? s2 : 0) * 20480 + 4096;
        bf16x8 af2[2][2], bf2r[4][2];
#pragma unroll
        for (int kk = 0; kk < 2; kk++) {
            int ck = s2 * 2 + kk;
#pragma unroll
            for (int mi = 0; mi < 2; mi++)
                af2[mi][kk] = *(const bf16x8*)(H
                    + (ck * 64 + wr * 32 + mi * 16 + l15) * 32 + sl);
#pragma unroll
            for (int ni = 0; ni < 4; ni++)
                bf2r[ni][kk] = *(const bf16x8*)(LB + kk * 8192
                    + (wc * 64 + ni * 16 + l15) * 32 + sl);
        }
        __builtin_amdgcn_s_setprio(1);
#pragma unroll
        for (int kk = 0; kk < 2; kk++)
#pragma unroll
            for (int mi = 0; mi < 2; mi++)
#pragma unroll
                for (int ni = 0; ni < 4; ni++)
                    acc2[mi][ni] = __builtin_amdgcn_mfma_f32_16x16x32_bf16(
                        af2[mi][kk], bf2r[ni][kk], acc2[mi][ni], 0, 0, 0);
        __builtin_amdgcn_s_setprio(0);
    }
#pragma unroll
    for (int mi = 0; mi < 2; mi++)
#pragma unroll
        for (int r = 0; r < 4; r++) {
            int lrow = wr * 32 + mi * 16 + hi * 4 + r;
            int pix = pix0 + lrow;
            int b = pix >> 10, Y = (pix >> 5) & 31, X = pix & 31;
            size_t base = (((size_t)b * 36 + Y + 2) * 36 + X + 2) * 256;
#pragma unroll
            for (int ni = 0; ni < 4; ni++) {
                int col = wc * 64 + ni * 16 + l15;
                float v = acc2[mi][ni][r] + bf2f(in[base + col]);
                outp[base + col] = f2bf(actf<OUTACT>(v));
            }
        }
}

// ------------------- old 4-wave gconv (tw0 parities, ew3) ------------------
template<int CIN, int COUT, int NTAPS, int TAPPAT, int SM, int INW,
         int OUTACT, bool RES, bool HASB, int OUTMODE, int BN>
__global__ __launch_bounds__(256) void gconv_k(
        const short* __restrict__ in, const short* __restrict__ Wp,
        const float* __restrict__ bias, const short* __restrict__ res,
        void* __restrict__ outp) {
    constexpr int KCH = CIN / 32;
    constexpr int LG = (KCH == 8) ? 3 : (KCH == 4) ? 2 : (KCH == 2) ? 1 : 0;
    constexpr int ST = NTAPS * KCH;
    constexpr int NF = BN / 32;
    constexpr int WN = BN / 2;
    __shared__ short sA[3 * 128 * 32];
    __shared__ short sB[3 * BN * 32];
    const int tid = threadIdx.x;
    const int lane = tid & 63, wv = tid >> 6;
    const int wr = wv >> 1, wc = wv & 1;
    const int pix0 = blockIdx.x * 128;
    const int oc0 = blockIdx.y * BN;
    int py = 0, px = 0;
    if (TAPPAT == 3) {
        int par = blockIdx.z;
        py = par >> 1; px = par & 1;
        Wp += (size_t)par * NTAPS * COUT * CIN;
    }

    const int sp = tid >> 2;
    const int fsp = fof(sp);
    const int swz = ((tid & 3) ^ fsp) * 8;
    int rbA[2];
#pragma unroll
    for (int rd = 0; rd < 2; rd++) {
        int pix = pix0 + sp + rd * 64;
        int b = pix >> 10, Y = (pix >> 5) & 31, X = pix & 31;
        rbA[rd] = ((b * INW + SM * Y + 2) * INW + (SM * X + 2)) * CIN + swz;
    }
    const int wb0 = (oc0 + sp) * CIN + swz;
    const int wb1 = (oc0 + sp + 64) * CIN + swz;

    f32x4 acc[4][NF];
#pragma unroll
    for (int i = 0; i < 4; i++)
#pragma unroll
        for (int j = 0; j < NF; j++) acc[i][j] = f32x4{0.f, 0.f, 0.f, 0.f};

    const int sslot = ((lane >> 4) ^ fof(lane & 15)) * 8;
    const int abase = (wr * 64 + (lane & 15)) * 32 + sslot;
    const int bbase = (wc * WN + (lane & 15)) * 32 + sslot;

    auto stage = [&](int s, int biq) {
        int t = s >> LG, c = s & (KCH - 1);
        int rof, cof;
        if (TAPPAT == 0) { rof = 0; cof = 0; }
        else if (TAPPAT == 1) { rof = t / 3 - 1; cof = t % 3 - 1; }
        else if (TAPPAT == 2) { rof = t / 4 - 1; cof = t % 4 - 1; }
        else { int my = t >> 1, mx = t & 1;
               rof = (py == 0) ? -my : 1 - my;
               cof = (px == 0) ? -mx : 1 - mx; }
        const int tapoff = (rof * INW + cof) * CIN + c * 32;
        char* a = (char*)sA + biq * 8192;
        char* b = (char*)sB + biq * (BN * 64);
        const short* wt = Wp + (size_t)t * COUT * CIN + c * 32;
        gload_lds16(in + rbA[0] + tapoff, a + tid * 16);
        gload_lds16(in + rbA[1] + tapoff, a + 4096 + tid * 16);
        gload_lds16(wt + wb0, b + tid * 16);
        if (BN == 128) gload_lds16(wt + wb1, b + 4096 + tid * 16);
    };

    stage(0, 0);
    stage(1, 1);
    int cur = 0;
    for (int s = 0; s < ST; ++s) {
        if (s < ST - 1) {
            if (BN == 128) { WAITV(4); } else { WAITV(3); }
        } else {
            WAITV(0);
        }
        __builtin_amdgcn_s_barrier();
        int nxt = cur + 2; if (nxt >= 3) nxt -= 3;
        if (s + 2 < ST) stage(s + 2, nxt);
        const short* a = sA + cur * 4096;
        const short* b = sB + cur * (BN * 32);
        bf16x8 af[4], bfm[NF];
#pragma unroll
        for (int mi = 0; mi < 4; mi++)
            af[mi] = *(const bf16x8*)(a + abase + mi * 512);
#pragma unroll
        for (int ni = 0; ni < NF; ni++)
            bfm[ni] = *(const bf16x8*)(b + bbase + ni * 512);
        __builtin_amdgcn_s_setprio(1);
#pragma unroll
        for (int mi = 0; mi < 4; mi++)
#pragma unroll
            for (int ni = 0; ni < NF; ni++)
                acc[mi][ni] = __builtin_amdgcn_mfma_f32_16x16x32_bf16(
                    af[mi], bfm[ni], acc[mi][ni], 0, 0, 0);
        __builtin_amdgcn_s_setprio(0);
        cur = (cur == 2) ? 0 : cur + 1;
    }
#pragma unroll
    for (int mi = 0; mi < 4; mi++) {
#pragma unroll
        for (int r = 0; r < 4; r++) {
            int pix = pix0 + wr * 64 + mi * 16 + (lane >> 4) * 4 + r;
            int b = pix >> 10, Y = (pix >> 5) & 31, X = pix & 31;
            size_t rowoff = 0;
            if (OUTMODE == 0)
                rowoff = (((size_t)b * 36 + Y + 2) * 36 + X + 2) * COUT;
            else if (OUTMODE == 2)
                rowoff = (((size_t)b * 68 + 2 * Y + py + 2) * 68 + 2 * X + px + 2) * 128;
#pragma unroll
            for (int ni = 0; ni < NF; ni++) {
                int col = oc0 + wc * WN + ni * 16 + (lane & 15);
                float v = acc[mi][ni][r];
                if (HASB) v += bias[col];
                if (OUTMODE == 1) {
                    ((float*)outp)[(size_t)pix * COUT + col] = actf<OUTACT>(v);
                } else {
                    size_t off = rowoff + col;
                    if (RES) v += bf2f(res[off]);
                    ((short*)outp)[off] = f2bf(actf<OUTACT>(v));
                }
            }
        }
    }
}

// ------------------------- conv0: 4x4 s2 p1, Cin=3 -------------------------
__global__ __launch_bounds__(256) void conv0_k(const float* __restrict__ x,
        const float* __restrict__ W, const float* __restrict__ bias,
        short* __restrict__ P0) {
    __shared__ float sIn[3 * 18 * 66];
    __shared__ float sW[48 * 32];
    int b = blockIdx.z, ocg = blockIdx.y, tile = blockIdx.x;
    int y0 = (tile >> 1) * 8, x0 = (tile & 1) * 32;
    int tid = threadIdx.x;
    for (int t = tid; t < 1536; t += 256) {
        int k = t >> 5, oc = t & 31;
        sW[t] = W[(size_t)(ocg * 32 + oc) * 48 + k];
    }
    for (int t = tid; t < 3 * 18 * 66; t += 256) {
        int ic = t / 1188; int rem = t - ic * 1188;
        int ry = rem / 66, rx = rem - ry * 66;
        int iy = 2 * y0 - 1 + ry, ix = 2 * x0 - 1 + rx;
        float v = 0.f;
        if ((unsigned)iy < 128u && (unsigned)ix < 128u)
            v = x[((size_t)b * 3 + ic) * 16384 + iy * 128 + ix];
        sIn[t] = v;
    }
    __syncthreads();
    int r = tid >> 5, cx = tid & 31;
    float acc[32];
#pragma unroll
    for (int o = 0; o < 32; o++) acc[o] = 0.f;
#pragma unroll
    for (int ic = 0; ic < 3; ic++) {
#pragma unroll
        for (int k = 0; k < 16; k++) {
            int ky = k >> 2, kx = k & 3;
            float xv = sIn[ic * 1188 + (2 * r + ky) * 66 + 2 * cx + kx];
            const float4* wp = (const float4*)(sW + (ic * 16 + k) * 32);
#pragma unroll
            for (int q = 0; q < 8; q++) {
                float4 w = wp[q];
                acc[4 * q + 0] += w.x * xv; acc[4 * q + 1] += w.y * xv;
                acc[4 * q + 2] += w.z * xv; acc[4 * q + 3] += w.w * xv;
            }
        }
    }
    size_t base = (((size_t)b * 68 + y0 + r + 2) * 68 + x0 + cx + 2) * 128 + ocg * 32;
#pragma unroll
    for (int q = 0; q < 16; q++) {
        float v0 = actf<2>(acc[2 * q] + bias[ocg * 32 + 2 * q]);
        float v1 = actf<2>(acc[2 * q + 1] + bias[ocg * 32 + 2 * q + 1]);
        ((int*)(P0 + base))[q] = (int)f2bfu(v0) | ((int)f2bfu(v1) << 16);
    }
}

// ------------------------------- VQ argmin (MFMA) --------------------------
__global__ __launch_bounds__(256) void vq_argmin_k(const float* __restrict__ zr,
        const float* __restrict__ cb, int* __restrict__ ind) {
    __shared__ short sZ[2][128 * 32];
    __shared__ short sC[2][128 * 32];
    __shared__ float sN[128];
    const int tid = threadIdx.x;
    const int lane = tid & 63, wv = tid >> 6;
    const int pos0 = blockIdx.x * 128;
#pragma unroll
    for (int it = 0; it < 4; ++it) {
        int task = tid + it * 256;
        int row = task >> 3, kq = task & 7;
        const float4* zp = (const float4*)(zr + (size_t)(pos0 + row) * 64 + kq * 8);
        float4 v0 = zp[0], v1 = zp[1];
        int slot = ((kq & 3) ^ fof(row)) * 8;
        short tmp[8] = {f2bf(v0.x), f2bf(v0.y), f2bf(v0.z), f2bf(v0.w),
                        f2bf(v1.x), f2bf(v1.y), f2bf(v1.z), f2bf(v1.w)};
        *(bf16x8*)&sZ[kq >> 2][row * 32 + slot] = *(bf16x8*)tmp;
    }
    const int sslot = ((lane >> 4) ^ fof(lane & 15)) * 8;
    const int l15 = lane & 15;
    float best[2][4]; int bidx[2][4];
#pragma unroll
    for (int mi = 0; mi < 2; mi++)
#pragma unroll
        for (int r = 0; r < 4; r++) { best[mi][r] = INFINITY; bidx[mi][r] = 0; }
    for (int ch = 0; ch < 4; ++ch) {
        __syncthreads();
#pragma unroll
        for (int it = 0; it < 4; ++it) {
            int task = tid + it * 256;
            int row = task >> 3, kq = task & 7;
            const float4* cp = (const float4*)(cb + (size_t)(ch * 128 + row) * 64 + kq * 8);
            float4 v0 = cp[0], v1 = cp[1];
            int slot = ((kq & 3) ^ fof(row)) * 8;
            short tmp[8] = {f2bf(v0.x), f2bf(v0.y), f2bf(v0.z), f2bf(v0.w),
                            f2bf(v1.x), f2bf(v1.y), f2bf(v1.z), f2bf(v1.w)};
            *(bf16x8*)&sC[kq >> 2][row * 32 + slot] = *(bf16x8*)tmp;
        }
        if (tid < 128) {
            const float4* cp = (const float4*)(cb + (size_t)(ch * 128 + tid) * 64);
            float s = 0.f;
#pragma unroll
            for (int q = 0; q < 16; q++) {
                float4 v = cp[q];
                s += v.x * v.x + v.y * v.y + v.z * v.z + v.w * v.w;
            }
            sN[tid] = s;
        }
        __syncthreads();
        f32x4 acc[2][8];
#pragma unroll
        for (int mi = 0; mi < 2; mi++)
#pragma unroll
            for (int ni = 0; ni < 8; ni++) acc[mi][ni] = f32x4{0.f, 0.f, 0.f, 0.f};
#pragma unroll
        for (int kc = 0; kc < 2; ++kc) {
            bf16x8 za[2], ca[8];
#pragma unroll
            for (int mi = 0; mi < 2; mi++)
                za[mi] = *(const bf16x8*)&sZ[kc][(wv * 32 + mi * 16 + l15) * 32 + sslot];
#pragma unroll
            for (int ni = 0; ni < 8; ni++)
                ca[ni] = *(const bf16x8*)&sC[kc][(ni * 16 + l15) * 32 + sslot];
#pragma unroll
            for (int mi = 0; mi < 2; mi++)
#pragma unroll
                for (int ni = 0; ni < 8; ni++)
                    acc[mi][ni] = __builtin_amdgcn_mfma_f32_16x16x32_bf16(
                        za[mi], ca[ni], acc[mi][ni], 0, 0, 0);
        }
#pragma unroll
        for (int mi = 0; mi < 2; mi++)
#pragma unroll
            for (int ni = 0; ni < 8; ni++) {
                float nrm = sN[ni * 16 + l15];
                int idx = ch * 128 + ni * 16 + l15;
#pragma unroll
                for (int r = 0; r < 4; r++) {
                    float sc = nrm - 2.f * acc[mi][ni][r];
                    if (sc < best[mi][r]) { best[mi][r] = sc; bidx[mi][r] = idx; }
                }
            }
    }
#pragma unroll
    for (int m = 1; m < 16; m <<= 1) {
#pragma unroll
        for (int mi = 0; mi < 2; mi++)
#pragma unroll
            for (int r = 0; r < 4; r++) {
                float os = __shfl_xor(best[mi][r], m);
                int   oi = __shfl_xor(bidx[mi][r], m);
                if (os < best[mi][r] || (os == best[mi][r] && oi < bidx[mi][r])) {
                    best[mi][r] = os; bidx[mi][r] = oi;
                }
            }
    }
    if (l15 == 0) {
        int g = lane >> 4;
#pragma unroll
        for (int mi = 0; mi < 2; mi++)
#pragma unroll
            for (int r = 0; r < 4; r++)
                ind[pos0 + wv * 32 + mi * 16 + g * 4 + r] = bidx[mi][r];
    }
}

// -------------- VQ gather -> Pq padded bf16 + loss partials ----------------
__global__ __launch_bounds__(256) void vq_gather_k(const float* __restrict__ zr,
        const float* __restrict__ cb, const int* __restrict__ ind,
        short* __restrict__ q, float* __restrict__ part) {
    int pos = blockIdx.x * 256 + threadIdx.x;
    int b = pos >> 10, hw = pos & 1023, y = hw >> 5, xx = hw & 31;
    int idx = ind[pos];
    const float4* cp = (const float4*)(cb + (size_t)idx * 64);
    const float4* zp = (const float4*)(zr + (size_t)pos * 64);
    size_t qb = (((size_t)b * 36 + y + 2) * 36 + xx + 2) * 64;
    float sum = 0.f;
#pragma unroll
    for (int d4 = 0; d4 < 16; d4++) {
        float4 c = cp[d4], z = zp[d4];
        float dx = c.x - z.x, dy = c.y - z.y, dz = c.z - z.z, dw = c.w - z.w;
        sum += dx * dx + dy * dy + dz * dz + dw * dw;
        ((int*)(q + qb))[2 * d4] = (int)f2bfu(c.x) | ((int)f2bfu(c.y) << 16);
        ((int*)(q + qb))[2 * d4 + 1] = (int)f2bfu(c.z) | ((int)f2bfu(c.w) << 16);
    }
#pragma unroll
    for (int m = 1; m < 64; m <<= 1) sum += __shfl_xor(sum, m);
    __shared__ float sred[4];
    int lane = threadIdx.x & 63, wvv = threadIdx.x >> 6;
    if (lane == 0) sred[wvv] = sum;
    __syncthreads();
    if (threadIdx.x == 0)
        part[blockIdx.x] = sred[0] + sred[1] + sred[2] + sred[3];
}

__global__ void finalize_k(const float* __restrict__ part, float* __restrict__ out) {
    if (threadIdx.x == 0) {
        float s = 0.f;
        for (int k = 0; k < 64; k++) s += part[k];
        float m = s / 1048576.f;
        out[786432] = m;
        out[786433] = m;
    }
}

// -------- tw1: ConvT 4x4 s2 p1, 128->3, input padded-68 bf16, tanh ---------
__global__ __launch_bounds__(256) void tw1_k(const short* __restrict__ in,
        const float* __restrict__ W, const float* __restrict__ bias,
        float* __restrict__ out) {
    __shared__ float sW[16 * 128 * 4];
    int b = blockIdx.y, y0 = blockIdx.x * 8;
    int tid = threadIdx.x;
    for (int t = tid; t < 2048; t += 256) {
        int k = t >> 7, ic = t & 127;
        float4 v;
        v.x = W[((size_t)ic * 3 + 0) * 16 + k];
        v.y = W[((size_t)ic * 3 + 1) * 16 + k];
        v.z = W[((size_t)ic * 3 + 2) * 16 + k];
        v.w = 0.f;
        *(float4*)&sW[t * 4] = v;
    }
    __syncthreads();
    int r = tid >> 5, g = tid & 31;
    int oy = y0 + r, py = oy & 1, Y = oy >> 1, pxp = g & 1;
    float acc[4][3];
#pragma unroll
    for (int p = 0; p < 4; p++)
#pragma unroll
        for (int o = 0; o < 3; o++) acc[p][o] = 0.f;
#pragma unroll
    for (int my = 0; my < 2; my++) {
        int iy = Y + ((py == 0) ? -my : 1 - my) + 2;
        const short* rowp = in + (((size_t)b * 68 + iy) * 68) * 128;
        int ky = 2 * my + (py ^ 1);
#pragma unroll
        for (int mx = 0; mx < 2; mx++) {
            int kx = 2 * mx + (pxp ^ 1);
            int cof = ((pxp == 0) ? -mx : 1 - mx) + 2;
            const float* wbase = &sW[((ky * 4 + kx) * 128) * 4];
            const short* pptr[4];
#pragma unroll
            for (int p = 0; p < 4; p++) {
                int X = ((g + 32 * p) >> 1) + cof;
                pptr[p] = rowp + (size_t)X * 128;
            }
            for (int icb = 0; icb < 16; icb++) {
                bf16x8 v[4];
#pragma unroll
                for (int p = 0; p < 4; p++)
                    v[p] = *(const bf16x8*)(pptr[p] + icb * 8);
#pragma unroll
                for (int j = 0; j < 8; j++) {
                    float4 w = *(const float4*)&wbase[(icb * 8 + j) * 4];
#pragma unroll
                    for (int p = 0; p < 4; p++) {
                        float xv = bf2f(v[p][j]);
                        acc[p][0] += w.x * xv;
                        acc[p][1] += w.y * xv;
                        acc[p][2] += w.z * xv;
                    }
                }
            }
        }
    }
#pragma unroll
    for (int p = 0; p < 4; p++) {
        int ox = g + 32 * p;
#pragma unroll
        for (int o = 0; o < 3; o++)
            out[(((size_t)b * 3 + o) << 14) + oy * 128 + ox] =
                tanhf(acc[p][o] + bias[o]);
    }
}

// ---------------------------------------------------------------------------
extern "C" void kernel_launch(void* const* d_in, const int* in_sizes, int n_in,
                              void* d_out, int out_size, void* d_ws, size_t ws_size,
                              hipStream_t stream) {
    const float* x    = (const float*)d_in[0];
    const float* ew0  = (const float*)d_in[1];
    const float* eb0  = (const float*)d_in[2];
    const float* ew1  = (const float*)d_in[3];
    const float* eb1  = (const float*)d_in[4];
    const float* ew2  = (const float*)d_in[5];
    const float* eb2  = (const float*)d_in[6];
    const float* erw3 = (const float*)d_in[7];
    const float* erw1 = (const float*)d_in[8];
    const float* ew3  = (const float*)d_in[9];
    const float* eb3  = (const float*)d_in[10];
    const float* cbk  = (const float*)d_in[11];
    const float* dw0  = (const float*)d_in[12];
    const float* db0  = (const float*)d_in[13];
    const float* drw3 = (const float*)d_in[14];
    const float* drw1 = (const float*)d_in[15];
    const float* tw0  = (const float*)d_in[16];
    const float* tb0  = (const float*)d_in[17];
    const float* tw1  = (const float*)d_in[18];
    const float* tb1  = (const float*)d_in[19];
    float* out = (float*)d_out;

    short* S = (short*)d_ws;
    short* P0  = S;                       // [16][68][68][128]
    short* PB  = P0 + 9469952;            // [16][36][36][256]
    short* PC  = PB + 5308416;
    short* Pq  = PC + 5308416;            // [16][36][36][64]
    short* Wp1 = Pq + 1327104;
    short* We2 = Wp1 + 524288;
    short* Wer3 = We2 + 589824;
    short* We11 = Wer3 + 3538944;
    short* Wz   = We11 + 393216;
    short* Wd0  = Wz + 16384;
    short* Wdr3 = Wd0 + 147456;
    short* Wdr1 = Wdr3 + 3538944;
    short* Wt0  = Wdr1 + 393216;
    float* F   = (float*)(S + 31080448);
    float* Zr  = F;                       // [16384][64]
    float* PART = Zr + 1048576;
    int*   IND = (int*)(PART + 64);

    hipMemsetAsync(d_ws, 0, (size_t)21413888 * 2, stream);

    auto gp = [](int n) { return dim3((n + 255) / 256); };
    prep_perm_k<<<gp(524288), 256, 0, stream>>>(ew1, Wp1, 256, 128, 16, 524288);
    prep_perm_k<<<gp(589824), 256, 0, stream>>>(ew2, We2, 256, 256, 9, 589824);
    prep_perm_k<<<gp(3538944), 256, 0, stream>>>(erw3, Wer3, 256, 256, 9, 3538944);
    prep_perm_k<<<gp(393216), 256, 0, stream>>>(erw1, We11, 256, 256, 1, 393216);
    prep_perm_k<<<gp(16384), 256, 0, stream>>>(ew3, Wz, 64, 256, 1, 16384);
    prep_perm_k<<<gp(147456), 256, 0, stream>>>(dw0, Wd0, 256, 64, 9, 147456);
    prep_perm_k<<<gp(3538944), 256, 0, stream>>>(drw3, Wdr3, 256, 256, 9, 3538944);
    prep_perm_k<<<gp(393216), 256, 0, stream>>>(drw1, Wdr1, 256, 256, 1, 393216);
    prep_tw0_k<<<gp(524288), 256, 0, stream>>>(tw0, Wt0);

    // ---------------- encoder ----------------
    conv0_k<<<dim3(16, 4, 16), 256, 0, stream>>>(x, ew0, eb0, P0);
    rconv_k<128, 16, 2, 2, 68, 2, true, false>
        <<<256, 512, 0, stream>>>(P0, Wp1, eb1, nullptr, PB);
    rconv_k<256, 9, 1, 1, 36, 2, true, false>
        <<<256, 512, 0, stream>>>(PB, We2, eb2, nullptr, PC);
    for (int i = 0; i < 6; i++) {
        short* inb  = (i & 1) ? PB : PC;
        short* outb = (i & 1) ? PC : PB;
        if (i < 5)
            rconv_k<256, 9, 1, 1, 36, 0, false, true>
                <<<256, 512, 0, stream>>>(inb, Wer3 + (size_t)i * 589824,
                    nullptr, We11 + (size_t)i * 65536, outb);
        else
            rconv_k<256, 9, 1, 1, 36, 2, false, true>
                <<<256, 512, 0, stream>>>(inb, Wer3 + (size_t)i * 589824,
                    nullptr, We11 + (size_t)i * 65536, outb);
    }
    // after 6 resblocks output is in PC
    gconv_k<256, 64, 1, 0, 1, 36, 2, false, true, 1, 64>
        <<<dim3(128, 1), 256, 0, stream>>>(PC, Wz, eb3, nullptr, Zr);

    // ---------------- vector quantization ----------------
    vq_argmin_k<<<128, 256, 0, stream>>>(Zr, cbk, IND);
    vq_gather_k<<<64, 256, 0, stream>>>(Zr, cbk, IND, Pq, PART);

    // ---------------- decoder ----------------
    rconv_k<64, 9, 1, 1, 36, 2, true, false>
        <<<256, 512, 0, stream>>>(Pq, Wd0, db0, nullptr, PC);
    for (int i = 0; i < 6; i++) {
        short* inb  = (i & 1) ? PB : PC;
        short* outb = (i & 1) ? PC : PB;
        if (i < 5)
            rconv_k<256, 9, 1, 1, 36, 0, false, true>
                <<<256, 512, 0, stream>>>(inb, Wdr3 + (size_t)i * 589824,
                    nullptr, Wdr1 + (size_t)i * 65536, outb);
        else
            rconv_k<256, 9, 1, 1, 36, 2, false, true>
                <<<256, 512, 0, stream>>>(inb, Wdr3 + (size_t)i * 589824,
                    nullptr, Wdr1 + (size_t)i * 65536, outb);
    }
    // tw0 ConvT 256->128: 4 parity GEMMs in one dispatch (z = parity)
    gconv_k<256, 128, 4, 3, 1, 36, 2, false, true, 2, 128>
        <<<dim3(128, 1, 4), 256, 0, stream>>>(PC, Wt0, tb0, nullptr, P0);
    tw1_k<<<dim3(16, 16), 256, 0, stream>>>(P0, tw1, tb1, out);

    finalize_k<<<1, 64, 0, stream>>>(PART, out);
}